// Round 8
// baseline (3656.341 us; speedup 1.0000x reference)
//
#include <hip/hip_runtime.h>
#include <cstdint>
#include <cstddef>

// MessagePassing (SCNN-style): 4 sequential directional scans.
// B=16 C=128 H=72 W=200 K=9 pad=4, fp32 in/out.
//
// Round-3 (PASS 6577us): relaxed agent-scope atomics, 1 block/(b,jc).
// Round-4/5 (FAIL): split (b,jc) ownership across blocks -> do not split.
// Round-6 (PASS 7502us): RELEASE flag regressed; "+v" pin spilled.
// Round-7 (PASS 4634us): own outputs kept in LDS ping-pong planes; only 8
//   halo cols cross blocks per step.
// Round-8 (PASS 3636us): 28 whi frags pinned in AGPRs ("+a" in-loop pins);
//   spin fused into per-thread halo wait. W step 5.93us, H step ~7.2us.
// Round-9 (infra failure: "container failed twice", no kernel signal;
//   deadlock audit clean: ring-of-4 staging safe at skew<=1, halo index
//   bijection verified, 208 blocks co-resident). Resubmitted unchanged:
//   - Producer epilogue already computes packed fp16 hi/lo u32s for its edge
//     cols -> ALSO writes them to compact staging stg[b][s&3][jc][side]
//     (1KB/side/plane-pair, mod-4 ring; neighbor skew <=1 -> 3 live slots).
//     Consumer halo = 512 coalesced u32 dev_loads (16 lines/plane) instead
//     of 1024 scattered fp32 (256 lines) + conversion. Bit-identical values.
//   - With halo via staging, NO in-pass cross-block data[] access remains
//     (cur = own cols; init row = pre-pass; inter-pass = kernel-boundary
//     coherence) -> ALL data[] loads/stores plain cached (write-back L2).
//     Pre-flag drain now covers only 4KB staging write-through, not 16KB.
//   - MFMA order/operands bit-exact; flag protocol unchanged -> absmax 0.25.

#define B_ 16
#define C_ 128
#define H_ 72
#define W_ 200
#define KW 9
#define NTOT (B_ * C_ * H_ * W_)

using f16x8 = _Float16 __attribute__((ext_vector_type(8)));
using f32x4 = float __attribute__((ext_vector_type(4)));

#define N_AGPR_FRAGS 28  // whi frags pinned to AGPRs (4 AGPR each)
#define NCH_MAX 13
#define STG_PER_B (4 * NCH_MAX * 2 * 512)  // slots x chunks x sides x (2 planes * 256 u32)

__device__ __forceinline__ unsigned pack_h2(_Float16 lo, _Float16 hi) {
  unsigned short a = __builtin_bit_cast(unsigned short, lo);
  unsigned short b = __builtin_bit_cast(unsigned short, hi);
  return (unsigned)a | ((unsigned)b << 16);
}

// device-coherent (MALL) access for cross-block staging/flags only
__device__ __forceinline__ unsigned dev_load_u32(const unsigned* p) {
  return __hip_atomic_load(p, __ATOMIC_RELAXED, __HIP_MEMORY_SCOPE_AGENT);
}
__device__ __forceinline__ void dev_store_u32(unsigned* p, unsigned v) {
  __hip_atomic_store(p, v, __ATOMIC_RELAXED, __HIP_MEMORY_SCOPE_AGENT);
}

// ---------------- copy x -> out ----------------
__global__ void copy_f4(const float4* __restrict__ src, float4* __restrict__ dst, int n4) {
  int i = blockIdx.x * blockDim.x + threadIdx.x;
  const int stride = gridDim.x * blockDim.x;
  for (; i < n4; i += stride) dst[i] = src[i];
}

// ---------------- transpose last two dims ----------------
template <int SH, int SW>
__global__ void transpose_hw(const float* __restrict__ src, float* __restrict__ dst) {
  __shared__ float t[32][33];
  const size_t base = (size_t)blockIdx.z * SH * SW;
  const int x = blockIdx.x * 32 + threadIdx.x;
#pragma unroll
  for (int j = 0; j < 4; ++j) {
    const int y = blockIdx.y * 32 + threadIdx.y + j * 8;
    if (y < SH && x < SW) t[threadIdx.y + j * 8][threadIdx.x] = src[base + (size_t)y * SW + x];
  }
  __syncthreads();
  const int x2 = blockIdx.y * 32 + threadIdx.x;
#pragma unroll
  for (int j = 0; j < 4; ++j) {
    const int y2 = blockIdx.x * 32 + threadIdx.y + j * 8;
    if (y2 < SW && x2 < SH) dst[base + (size_t)y2 * SH + x2] = t[threadIdx.x][threadIdx.y + j * 8];
  }
}

// ---------------- weight repack: wgt[co][ci][dk] -> MFMA A-frag order ----------------
// frag index: [cot(8)][t(36)][lane(64)] f16x8; lane: m=lane&15 (co), q=lane>>4;
// element j <-> k = t*32 + q*8 + j, k = dk*128 + ci (dk = t>>2, ci = (t&3)*32 + q*8 + j)
__global__ void repack_w(const float* __restrict__ wgt, f16x8* __restrict__ whi,
                         f16x8* __restrict__ wlo) {
  const int blk = blockIdx.x;  // cot*36 + t
  const int cot = blk / 36, t = blk % 36;
  const int lane = threadIdx.x;
  const int n = lane & 15, q = lane >> 4;
  const int co = cot * 16 + n, dk = t >> 2, ci0 = (t & 3) * 32 + q * 8;
  f16x8 h, l;
#pragma unroll
  for (int j = 0; j < 8; ++j) {
    const float w = wgt[((size_t)co * C_ + ci0 + j) * KW + dk];
    const _Float16 hh = (_Float16)w;
    h[j] = hh;
    l[j] = (_Float16)(w - (float)hh);
  }
  whi[(size_t)blk * 64 + lane] = h;
  wlo[(size_t)blk * 64 + lane] = l;
}

// ---------------- MFMA scan pass ----------------
// data[b][c][RDIM][WDIM]; scan RDIM rows; conv (K=9,pad4) over contiguous WDIM.
// grid = 16*NCH blocks: b = bx&15, chunk jc = bx>>4 (16 positions).
// fp16 planes ping-pong in LDS; own cols wi 4..19 from epilogue registers;
// halo wi 0..3 / 20..23 from compact staging written by the neighbor.
template <int RDIM, int WDIM, int NCH>
__global__ __launch_bounds__(512, 1) void pass_mfma(float* __restrict__ data,
                                                    const f16x8* __restrict__ whi,
                                                    const f16x8* __restrict__ wlo,
                                                    unsigned* flags, unsigned* stg,
                                                    const int dir) {
  constexpr int RW = RDIM * WDIM;
  constexpr int PL = 24 * 68;  // u32 per plane buffer: [wi(24)][ci-pair pad 68]
  __shared__ __align__(16) unsigned fh[2 * PL];
  __shared__ __align__(16) unsigned fl[2 * PL];

  const int tid = threadIdx.x;
  const int wave = tid >> 6, lane = tid & 63;
  const int n = lane & 15, q = lane >> 4;
  const int b = blockIdx.x & 15, jc = blockIdx.x >> 4;
  const int pos_base = jc * 16;
  const int pos = pos_base + n;
  const size_t bbase = (size_t)b * C_ * RW;
  unsigned* stgB = stg + (size_t)b * STG_PER_B;

  // persistent A-frags (Whi); first N_AGPR_FRAGS pinned to AGPRs in-loop
  f16x8 ahi[36];
#pragma unroll
  for (int t = 0; t < 36; ++t) ahi[t] = whi[(size_t)(wave * 36 + t) * 64 + lane];
  const f16x8* wloL = wlo + (size_t)wave * 36 * 64 + lane;

  // halo-thread geometry (each of 512 threads owns one (wi, ci-pair))
  const int h_wi8 = tid >> 6, h_c2 = tid & 63;
  const int h_wi = (h_wi8 < 4) ? h_wi8 : (h_wi8 + 16);  // 0..3 and 20..23
  const int h_p = pos_base - 4 + h_wi;
  const bool h_valid = (h_p >= 0 && h_p < WDIM);
  const int h_jn = (h_wi < 4) ? (jc - 1) : (jc + 1);    // producer chunk
  const int h_side = (h_wi8 < 4) ? 1 : 0;               // producer's edge side
  const int h_wip = (h_wi8 < 4) ? h_wi8 : (h_wi8 - 4);  // wi' within edge

  // ---- init: fill plane buffer 0 with full 24-wi window of row r0 ----
  // row r0 is pre-pass data (written by a previous kernel) -> plain cached.
  {
    const int r0 = (dir > 0) ? 0 : (RDIM - 1);
#pragma unroll
    for (int i = 0; i < 3; ++i) {
      const int idx = tid + 512 * i;  // 1536 = 24 wi * 64 ci-pairs
      const int wi = idx >> 6, c2 = idx & 63;
      const int p = pos_base - 4 + wi;
      float x0 = 0.f, x1 = 0.f;
      if (p >= 0 && p < WDIM) {
        x0 = data[bbase + (size_t)(2 * c2) * RW + (size_t)r0 * WDIM + p];
        x1 = data[bbase + (size_t)(2 * c2 + 1) * RW + (size_t)r0 * WDIM + p];
      }
      const _Float16 h0 = (_Float16)x0, h1 = (_Float16)x1;
      const _Float16 l0 = (_Float16)(x0 - (float)h0), l1 = (_Float16)(x1 - (float)h1);
      fh[wi * 68 + c2] = pack_h2(h0, h1);
      fl[wi * 68 + c2] = pack_h2(l0, l1);
    }
  }
  __syncthreads();  // init fence

  for (int s = 1; s < RDIM; ++s) {
    const int r = (dir > 0) ? s : (RDIM - 1 - s);
    const int rp = r - dir;          // producer row
    const int pb = (s - 1) & 1;      // plane buffer holding row rp
    const int cb = s & 1;            // plane buffer to fill with row r

    // AGPR pin: forces whi[0..27] to live in AGPRs across the loop
#pragma unroll
    for (int t = 0; t < N_AGPR_FRAGS; ++t) asm volatile("" : "+a"(ahi[t]));

    // preload current row r: never written before this step in this pass;
    // plain cached load issued before the spin to hide latency.
    float cur[4];
#pragma unroll
    for (int reg = 0; reg < 4; ++reg) {
      const int co = wave * 16 + q * 4 + reg;
      cur[reg] = (pos < WDIM) ? data[bbase + (size_t)co * RW + (size_t)r * WDIM + pos] : 0.f;
    }

    // fused spin + halo fill from compact staging (coalesced u32 reads).
    if (s > 1) {
      unsigned uh = 0, ul = 0;
      if (h_valid) {
        unsigned* f = &flags[((size_t)b * RDIM + rp) * NCH + h_jn];
        while (__hip_atomic_load(f, __ATOMIC_RELAXED, __HIP_MEMORY_SCOPE_AGENT) == 0u)
          __builtin_amdgcn_s_sleep(1);
        const unsigned* sb = stgB +
            ((size_t)(((s - 1) & 3) * NCH + h_jn) * 2 + h_side) * 512 + h_wip * 64 + h_c2;
        uh = dev_load_u32(sb);
        ul = dev_load_u32(sb + 256);
      }
      fh[pb * PL + h_wi * 68 + h_c2] = uh;
      fl[pb * PL + h_wi * 68 + h_c2] = ul;
    }
    __syncthreads();  // (B) planes[pb] complete

    // MFMA: D[co16 x pos16], K = 1152 (36 k-tiles), 3-term split.
    // BIT-EXACT order: t ascending, 3 separate accumulators.
    f32x4 aA = {0.f, 0.f, 0.f, 0.f}, aB = {0.f, 0.f, 0.f, 0.f}, aC = {0.f, 0.f, 0.f, 0.f};
#pragma unroll
    for (int t = 0; t < 36; ++t) {
      const int dk = t >> 2;
      const int off = pb * PL + (n + dk) * 68 + (t & 3) * 16 + q * 4;  // 16B-aligned
      const f16x8 bh = *(const f16x8*)&fh[off];
      const f16x8 bl = *(const f16x8*)&fl[off];
      const f16x8 al = wloL[(size_t)t * 64];
      aA = __builtin_amdgcn_mfma_f32_16x16x32_f16(ahi[t], bh, aA, 0, 0, 0);
      aB = __builtin_amdgcn_mfma_f32_16x16x32_f16(ahi[t], bl, aB, 0, 0, 0);
      aC = __builtin_amdgcn_mfma_f32_16x16x32_f16(al, bh, aC, 0, 0, 0);
    }

    // epilogue: C/D layout col=lane&15 (pos), row=q*4+reg (co-within-tile).
    float resv[4];
#pragma unroll
    for (int reg = 0; reg < 4; ++reg) {
      const float v = aA[reg] + aB[reg] + aC[reg];
      resv[reg] = (pos < WDIM) ? (cur[reg] + fmaxf(v, 0.f)) : 0.f;
    }
    // plain cached stores (no in-pass cross-block reader of data[])
    if (pos < WDIM) {
#pragma unroll
      for (int reg = 0; reg < 4; ++reg) {
        const int co = wave * 16 + q * 4 + reg;
        data[bbase + (size_t)co * RW + (size_t)r * WDIM + pos] = resv[reg];
      }
    }
    // convert own cols into planes[cb]; edge threads also stage for neighbors
    {
      const _Float16 h0 = (_Float16)resv[0], h1 = (_Float16)resv[1];
      const _Float16 l0 = (_Float16)(resv[0] - (float)h0), l1 = (_Float16)(resv[1] - (float)h1);
      const _Float16 h2 = (_Float16)resv[2], h3 = (_Float16)resv[3];
      const _Float16 l2 = (_Float16)(resv[2] - (float)h2), l3 = (_Float16)(resv[3] - (float)h3);
      const unsigned uh0 = pack_h2(h0, h1), uh1 = pack_h2(h2, h3);
      const unsigned ul0 = pack_h2(l0, l1), ul1 = pack_h2(l2, l3);
      const int base = cb * PL + (n + 4) * 68 + wave * 8 + q * 2;
      fh[base] = uh0;
      fh[base + 1] = uh1;
      fl[base] = ul0;
      fl[base + 1] = ul1;
      if (n < 4 || n >= 12) {
        const int side = (n < 4) ? 0 : 1;
        const int wip = (n < 4) ? n : (n - 12);
        unsigned* sb = stgB + ((size_t)((s & 3) * NCH + jc) * 2 + side) * 512 + wip * 64 +
                       (wave * 8 + q * 2);
        dev_store_u32(sb, uh0);
        dev_store_u32(sb + 1, uh1);
        dev_store_u32(sb + 256, ul0);
        dev_store_u32(sb + 256 + 1, ul1);
      }
    }
    __syncthreads();  // (C) drains vmcnt -> staging visible before flag
    if (tid == 0)
      __hip_atomic_store(&flags[((size_t)b * RDIM + r) * NCH + jc], 1u, __ATOMIC_RELAXED,
                         __HIP_MEMORY_SCOPE_AGENT);
  }
}

extern "C" void kernel_launch(void* const* d_in, const int* in_sizes, int n_in, void* d_out,
                              int out_size, void* d_ws, size_t ws_size, hipStream_t stream) {
  const float* x = (const float*)d_in[0];
  const float* w_down = (const float*)d_in[1];
  const float* w_up = (const float*)d_in[2];
  const float* w_right = (const float*)d_in[3];
  const float* w_left = (const float*)d_in[4];
  float* out = (float*)d_out;

  // ---- ws layout ----
  // [0, 256K):                 flags (memset 0)
  // [256K, 2,621,440):         weight frag planes (hi,lo) x 4 passes
  // [2,621,440, 6,029,312):    halo staging ring (shared across passes)
  // [6,029,312, ...):          transpose scratch T if it fits, else d_in[0]
  unsigned* flags = (unsigned*)d_ws;
  unsigned* f_down = flags;                      // 72*13*16 = 14976
  unsigned* f_up = f_down + H_ * 13 * B_;        // 14976
  unsigned* f_right = f_up + H_ * 13 * B_;       // 200*5*16 = 16000
  unsigned* f_left = f_right + W_ * 5 * B_;      // 16000
  hipMemsetAsync(d_ws, 0, 262144, stream);

  const size_t PLANE = (size_t)8 * 36 * 64;  // f16x8 elements per plane = 294912 B
  f16x8* wf = (f16x8*)((char*)d_ws + 262144);
  f16x8* whi_d = wf + 0 * PLANE;
  f16x8* wlo_d = wf + 1 * PLANE;
  f16x8* whi_u = wf + 2 * PLANE;
  f16x8* wlo_u = wf + 3 * PLANE;
  f16x8* whi_r = wf + 4 * PLANE;
  f16x8* wlo_r = wf + 5 * PLANE;
  f16x8* whi_l = wf + 6 * PLANE;
  f16x8* wlo_l = wf + 7 * PLANE;

  unsigned* stg = (unsigned*)((char*)d_ws + 2621440);  // 16*4*13*2*512*4 = 3,407,872 B

  const size_t toff = 2621440 + (size_t)B_ * STG_PER_B * 4;
  const size_t tbytes = (size_t)NTOT * sizeof(float);
  float* T = (ws_size >= toff + tbytes) ? (float*)((char*)d_ws + toff) : (float*)d_in[0];

  // weight repack (one-time per launch)
  repack_w<<<288, 64, 0, stream>>>(w_down, whi_d, wlo_d);
  repack_w<<<288, 64, 0, stream>>>(w_up, whi_u, wlo_u);
  repack_w<<<288, 64, 0, stream>>>(w_right, whi_r, wlo_r);
  repack_w<<<288, 64, 0, stream>>>(w_left, whi_l, wlo_l);

  // out = x
  copy_f4<<<1024, 256, 0, stream>>>((const float4*)x, (float4*)out, NTOT / 4);

  // down/up: scan h (RDIM=72), conv over w (WDIM=200, 13 chunks) -> 208 blocks
  pass_mfma<H_, W_, 13><<<16 * 13, 512, 0, stream>>>(out, whi_d, wlo_d, f_down, stg, +1);
  pass_mfma<H_, W_, 13><<<16 * 13, 512, 0, stream>>>(out, whi_u, wlo_u, f_up, stg, -1);

  // transpose [b,c,h,w] -> [b,c,w,h]
  {
    dim3 g((W_ + 31) / 32, (H_ + 31) / 32, B_ * C_);
    transpose_hw<H_, W_><<<g, dim3(32, 8), 0, stream>>>(out, T);
  }

  // right/left: scan w (RDIM=200), conv over h (WDIM=72, 5 chunks) -> 80 blocks
  pass_mfma<W_, H_, 5><<<16 * 5, 512, 0, stream>>>(T, whi_r, wlo_r, f_right, stg, +1);
  pass_mfma<W_, H_, 5><<<16 * 5, 512, 0, stream>>>(T, whi_l, wlo_l, f_left, stg, -1);

  // transpose back
  {
    dim3 g((H_ + 31) / 32, (W_ + 31) / 32, B_ * C_);
    transpose_hw<W_, H_><<<g, dim3(32, 8), 0, stream>>>(T, out);
  }
}